// Round 15
// baseline (590.361 us; speedup 1.0000x reference)
//
#include <hip/hip_runtime.h>

typedef unsigned short u16;
typedef unsigned char u8;
typedef unsigned int u32;
typedef long i64;
typedef __attribute__((ext_vector_type(8))) short bf16x8;
typedef __attribute__((ext_vector_type(4))) float f32x4;
typedef __attribute__((ext_vector_type(16))) float f32x16;
typedef __attribute__((ext_vector_type(4))) u16 u16x4;
typedef __attribute__((ext_vector_type(4))) u32 u32x4;

__device__ __forceinline__ u16 f2bf(float f) {
  u32 u = __builtin_bit_cast(u32, f);
  return (u16)((u + 0x7FFFu + ((u >> 16) & 1u)) >> 16);
}
__device__ __forceinline__ u8 f2fp8(float f) {
  int w = __builtin_amdgcn_cvt_pk_fp8_f32(f, 0.f, 0, false);
  return (u8)(w & 0xff);
}

__device__ __forceinline__ f32x4 mfma16(bf16x8 a, bf16x8 b, f32x4 c) {
  return __builtin_amdgcn_mfma_f32_16x16x32_bf16(a, b, c, 0, 0, 0);
}
__device__ __forceinline__ f32x16 mfma32(bf16x8 a, bf16x8 b, f32x16 c) {
  return __builtin_amdgcn_mfma_f32_32x32x16_bf16(a, b, c, 0, 0, 0);
}
__device__ __forceinline__ f32x16 mfma32f8(i64 a, i64 b, f32x16 c) {
  return __builtin_amdgcn_mfma_f32_32x32x16_fp8_fp8(a, b, c, 0, 0, 0);
}

__device__ __forceinline__ void gload16(const void* g, void* l) {
  __builtin_amdgcn_global_load_lds(
      (const __attribute__((address_space(1))) unsigned int*)g,
      (__attribute__((address_space(3))) unsigned int*)l, 16, 0, 0);
}

__device__ __forceinline__ u32 cvtpk(float lo, float hi) {
  u32 r;
  asm volatile("v_cvt_pk_bf16_f32 %0, %1, %2" : "=v"(r) : "v"(lo), "v"(hi));
  return r;
}
__device__ __forceinline__ void pl32swap(u32& a, u32& b) {
  asm volatile("v_permlane32_swap_b32 %0, %1" : "+v"(a), "+v"(b));
}

// ---------------- pack kernels ----------------

__global__ void pack_x_kernel(const float* __restrict__ x, u16* __restrict__ xb) {
  const int i = blockIdx.x * 256 + threadIdx.x;
  const float4 v = ((const float4*)x)[i];
  u16x4 o;
  o[0] = f2bf(v.x); o[1] = f2bf(v.y); o[2] = f2bf(v.z); o[3] = f2bf(v.w);
  ((u16x4*)xb)[i] = o;
}

// W: [512][4096] col = k*8+h  ->  Wp: [h*512+k][dd]  (tiled LDS transpose)
__global__ void pack_wqkv_t(const float* __restrict__ W, u16* __restrict__ Wp) {
  __shared__ u16 tile[64][72];
  const int t = threadIdx.x;
  const int c0 = blockIdx.x * 64, dd0 = blockIdx.y * 64;
#pragma unroll
  for (int s = 0; s < 4; ++s) {
    const int r = s * 16 + (t >> 4);
    const int q = (t & 15) * 4;
    const float4 v = *(const float4*)&W[(size_t)(dd0 + r) * 4096 + c0 + q];
    tile[r][q + 0] = f2bf(v.x); tile[r][q + 1] = f2bf(v.y);
    tile[r][q + 2] = f2bf(v.z); tile[r][q + 3] = f2bf(v.w);
  }
  __syncthreads();
#pragma unroll
  for (int s = 0; s < 4; ++s) {
    const int cl = s * 16 + (t >> 4);
    const int u = t & 15;
    const int cg = c0 + cl;
    const int orow = (cg & 7) * 512 + (cg >> 3);
    u16x4 o;
#pragma unroll
    for (int i = 0; i < 4; ++i) o[i] = tile[u * 4 + i][cl];
    *(u16x4*)&Wp[(size_t)orow * 512 + dd0 + u * 4] = o;
  }
}

// Wo: [4096][512] -> Wot: [n=512][k=4096]
__global__ void pack_wo_t(const float* __restrict__ W, u16* __restrict__ Wp) {
  __shared__ u16 tile[64][72];
  const int t = threadIdx.x;
  const int k0 = blockIdx.x * 64, n0 = blockIdx.y * 64;
#pragma unroll
  for (int s = 0; s < 4; ++s) {
    const int r = s * 16 + (t >> 4);
    const int q = (t & 15) * 4;
    const float4 v = *(const float4*)&W[(size_t)(k0 + r) * 512 + n0 + q];
    tile[r][q + 0] = f2bf(v.x); tile[r][q + 1] = f2bf(v.y);
    tile[r][q + 2] = f2bf(v.z); tile[r][q + 3] = f2bf(v.w);
  }
  __syncthreads();
#pragma unroll
  for (int s = 0; s < 4; ++s) {
    const int cl = s * 16 + (t >> 4);
    const int u = t & 15;
    u16x4 o;
#pragma unroll
    for (int i = 0; i < 4; ++i) o[i] = tile[u * 4 + i][cl];
    *(u16x4*)&Wp[(size_t)(n0 + cl) * 4096 + k0 + u * 4] = o;
  }
}

// ---------------- GEMM: C[M][N] = A[M][Kd] * B[N][Kd]^T ----------------
// MODE 0: fp8 -> [bh][t][d] (*scale)                   (Q)
// MODE 1: bf16 transposed -> Vt [bh][d][t]             (V)
// MODE 2: fp32 + bias -> [row][512]                    (out)
// MODE 3: fp8 K4-tiled [bh][t/32][k/16][t&31][16B] (*scale)  (K)

template <int MODE>
__global__ __launch_bounds__(256, 2) void gemm_bf16(
    const u16* __restrict__ A, const u16* __restrict__ B,
    void* __restrict__ Cout, const float* __restrict__ bias,
    int Kd, float scale) {
  __shared__ u16 Al[128 * 64];
  __shared__ u16 Bl[128 * 64];
  const int tid = threadIdx.x;
  const int lane = tid & 63;
  const int w = tid >> 6, wm = w >> 1, wn = w & 1;
  const int l15 = lane & 15, lg = lane >> 4;
  const int m0 = blockIdx.y * 128, n0 = blockIdx.x * 128;

  f32x4 acc[4][4];
  const f32x4 zero = {0.f, 0.f, 0.f, 0.f};
#pragma unroll
  for (int i = 0; i < 4; ++i)
#pragma unroll
    for (int j = 0; j < 4; ++j) acc[i][j] = zero;

  const int nk = Kd >> 6;
  for (int kt = 0; kt < nk; ++kt) {
    __syncthreads();
    const int k0 = kt << 6;
#pragma unroll
    for (int s = 0; s < 4; ++s) {
      const int chunk = s * 256 + tid;
      const int row = chunk >> 3, c = chunk & 7;
      const int cs = c ^ (row & 7);
      gload16(A + (size_t)(m0 + row) * Kd + k0 + cs * 8, &Al[chunk * 8]);
    }
#pragma unroll
    for (int s = 0; s < 4; ++s) {
      const int chunk = s * 256 + tid;
      const int row = chunk >> 3, c = chunk & 7;
      const int cs = c ^ (row & 7);
      gload16(B + (size_t)(n0 + row) * Kd + k0 + cs * 8, &Bl[chunk * 8]);
    }
    __syncthreads();
#pragma unroll
    for (int kk = 0; kk < 2; ++kk) {
      bf16x8 af[4], bfr[4];
      const int ch = kk * 4 + lg;
#pragma unroll
      for (int i = 0; i < 4; ++i) {
        const int ar = wm * 64 + i * 16 + l15;
        af[i] = *(const bf16x8*)&Al[ar * 64 + ((ch ^ (ar & 7)) * 8)];
        const int br = wn * 64 + i * 16 + l15;
        bfr[i] = *(const bf16x8*)&Bl[br * 64 + ((ch ^ (br & 7)) * 8)];
      }
#pragma unroll
      for (int i = 0; i < 4; ++i)
#pragma unroll
        for (int j = 0; j < 4; ++j)
          acc[i][j] = mfma16(af[i], bfr[j], acc[i][j]);
    }
  }

#pragma unroll
  for (int i = 0; i < 4; ++i) {
    const int gr0 = m0 + wm * 64 + i * 16 + lg * 4;
#pragma unroll
    for (int j = 0; j < 4; ++j) {
      const int gc = n0 + wn * 64 + j * 16 + l15;
      if constexpr (MODE == 0) {
        u8* O = (u8*)Cout;
        const int h = gc >> 9, d = gc & 511;
#pragma unroll
        for (int r = 0; r < 4; ++r) {
          const int grr = gr0 + r;
          const int bb = grr >> 11, t = grr & 2047;
          O[((size_t)((bb * 8 + h) * 2048 + t) << 9) + d] = f2fp8(acc[i][j][r] * scale);
        }
      } else if constexpr (MODE == 1) {
        u16* O = (u16*)Cout;
        const int h = gc >> 9, d = gc & 511;
        const int bb = gr0 >> 11, t = gr0 & 2047;
        u16x4 pk;
#pragma unroll
        for (int r = 0; r < 4; ++r) pk[r] = f2bf(acc[i][j][r]);
        *(u16x4*)&O[((size_t)((bb * 8 + h) * 512 + d) << 11) + t] = pk;
      } else if constexpr (MODE == 3) {
        u8* O = (u8*)Cout;
        const int h = gc >> 9, k = gc & 511;
#pragma unroll
        for (int r = 0; r < 4; ++r) {
          const int grr = gr0 + r;
          const int bb = grr >> 11, t = grr & 2047;
          O[((((size_t)(bb * 8 + h) * 64 + (t >> 5)) * 32 + (k >> 4)) * 32 + (t & 31)) * 16 +
            (k & 15)] = f2fp8(acc[i][j][r] * scale);
        }
      } else {
        float* O = (float*)Cout;
        const float bv = bias[gc];
#pragma unroll
        for (int r = 0; r < 4; ++r)
          O[(size_t)(gr0 + r) * 512 + gc] = acc[i][j][r] + bv;
      }
    }
  }
}

// ---------------- flash attention v15: single-barrier lagged pipeline ----------------
// Q fp8: [bh][2048][512]B; K4 fp8 tiled: [bh][64][32][32][16B]; Vt bf16: [bh][512][2048];
// Og bf16: [bb*2048+t][h*512+d]
// block = 8 waves = 4 pairs; pair owns 32 q rows (128 q/block); wave k/d-half = 256.
// KV block 32, 64 steps. LDS = V3 tribuf 3x32K + Sxf parity-dbuf 2x32K = 163840 B.
// Step t: stage V(t+1)->(t+1)%3 | QKT(t) (K regs) | kf prefetch(t+1) |
//         Sxf[t&1] write | lagged{combine(t-1) from Sxf[(t-1)&1], exp, pf, PV(t-1)} |
//         ONE s_waitcnt vmcnt(0) lgkmcnt(0) + s_barrier.
// Hazards (ledgered): Sxf parity alternates (write t vs read t-1 disjoint; same-parity
// reuse separated by 2 end-barriers). V(x): staged t=x-1, read t=x+1, rewritten t=x+2.
// No setprio, no sched_barrier (schedule left to compiler; m141/m190 lessons).
// Softmax: constant-m (|s| ~ 0.2 << 88; exact softmax, r14-verified).

__global__ __launch_bounds__(512, 2) void attn_kernel(
    const u8* __restrict__ Qg, const u8* __restrict__ K4g,
    const u16* __restrict__ Vtg, u16* __restrict__ Og, int nbh_pxcd) {
  __shared__ u16 V3[3][512 * 32];      // [buf][d][kv]  8-u16-chunk swz: c ^ ((d>>1)&3)
  __shared__ float Sxf[2][8][32][32];  // [parity][wave][q-lane][slots] slot-swizzled

  const int tid = threadIdx.x;
  const int lane = tid & 63;
  const int w = tid >> 6;
  const int pr = w >> 1, whalf = w & 1;
  const int l31 = lane & 31, hi = lane >> 5;

  const int bid = blockIdx.x;
  const int x8 = bid & 7, rest = bid >> 3;
  const int qt = rest & 15;
  const int bh = x8 * nbh_pxcd + (rest >> 4);

  const u8* Qb = Qg + (size_t)bh * 2048 * 512;
  const u8* K4b = K4g + (size_t)bh * 2048 * 512;
  const u16* Vb = Vtg + (size_t)bh * 2048 * 512;

  // Q fp8 B-fragments: lane holds Q[q=l31][k = whalf*256 + cc*16 + hi*8 + j]
  const int qrow = qt * 128 + pr * 32 + l31;
  i64 qf8[16];
  {
    const u8* qp = Qb + (size_t)qrow * 512 + whalf * 256 + hi * 8;
#pragma unroll
    for (int cc = 0; cc < 16; ++cc) qf8[cc] = *(const i64*)(qp + cc * 16);
  }

  // per-lane K4 offset inside a tile: chunk cc at koff + cc*512
  const int koff = whalf * 16 * 512 + l31 * 16 + hi * 8;

  f32x16 acc[8];
#pragma unroll
  for (int i = 0; i < 8; ++i) acc[i] = {};
  float lsum = 0.f;
  f32x16 sprev;  // partial S(t-1), carried

#define STAGE_V(tile, buf)                                                    \
  {                                                                           \
    _Pragma("unroll") for (int s_ = 0; s_ < 4; ++s_) {                        \
      const int chunk = s_ * 512 + tid;                                       \
      const int row = chunk >> 2, c_ = chunk & 3;                             \
      const int cs = c_ ^ ((row >> 1) & 3);                                   \
      gload16(Vb + (size_t)row * 2048 + (tile) * 32 + cs * 8,                 \
              &V3[buf][chunk * 8]);                                           \
    }                                                                         \
  }

  // lagged block: combine sprev with partner partial (parity p), exp, pf, PV(buf)
#define LAGGED(p, vbuf)                                                       \
  {                                                                           \
    const float* sp = &Sxf[p][w ^ 1][l31][0];                                 \
    _Pragma("unroll") for (int g = 0; g < 4; ++g) {                           \
      const int slot = (2 * g + hi) ^ (l31 & 7);                              \
      const f32x4 v_ = *(const f32x4*)&sp[slot * 4];                          \
      _Pragma("unroll") for (int jj = 0; jj < 4; ++jj)                        \
          sprev[4 * g + jj] += v_[jj];                                        \
    }                                                                         \
    _Pragma("unroll") for (int r = 0; r < 16; ++r) {                          \
      sprev[r] = __expf(sprev[r]);                                            \
      lsum += sprev[r];                                                       \
    }                                                                         \
    bf16x8 pf0, pf1;                                                          \
    {                                                                         \
      u32 wd[8];                                                              \
      _Pragma("unroll") for (int g = 0; g < 4; ++g) {                         \
        wd[2 * g] = cvtpk(sprev[4 * g + 0], sprev[4 * g + 1]);                \
        wd[2 * g + 1] = cvtpk(sprev[4 * g + 2], sprev[4 * g + 3]);            \
      }                                                                       \
      pl32swap(wd[0], wd[2]); pl32swap(wd[1], wd[3]);                         \
      pl32swap(wd[4], wd[6]); pl32swap(wd[5], wd[7]);                         \
      u32x4 f0_ = {wd[0], wd[1], wd[2], wd[3]};                               \
      u32x4 f1_ = {wd[4], wd[5], wd[6], wd[7]};                               \
      pf0 = __builtin_bit_cast(bf16x8, f0_);                                  \
      pf1 = __builtin_bit_cast(bf16x8, f1_);                                  \
    }                                                                         \
    _Pragma("unroll") for (int blk = 0; blk < 8; ++blk) {                     \
      const int drow = whalf * 256 + blk * 32 + l31;                          \
      const int pos0 = hi ^ ((drow >> 1) & 3);                                \
      const int pos1 = (2 + hi) ^ ((drow >> 1) & 3);                          \
      bf16x8 v0 = *(const bf16x8*)&V3[vbuf][drow * 32 + pos0 * 8];            \
      bf16x8 v1 = *(const bf16x8*)&V3[vbuf][drow * 32 + pos1 * 8];            \
      acc[blk] = mfma32(v0, pf0, acc[blk]);                                   \
      acc[blk] = mfma32(v1, pf1, acc[blk]);                                   \
    }                                                                         \
  }

  // -------- prologue: stage V(0)->buf0, preload K(0) frags --------
  STAGE_V(0, 0);
  i64 kf[16];
  {
    const u8* kp = K4b + koff;
#pragma unroll
    for (int cc = 0; cc < 16; ++cc) kf[cc] = *(const i64*)(kp + cc * 512);
  }
  asm volatile("s_waitcnt vmcnt(0)" ::: "memory");
  __builtin_amdgcn_s_barrier();

  int vstage = 1;  // (t+1)%3
  int vread = 2;   // (t-1)%3 (valid for t>=1)

  for (int t = 0; t < 64; ++t) {
    // stage V(t+1) (in flight across whole step; convoy pacing)
    if (t < 63) STAGE_V(t + 1, vstage);

    // QKT(t): S^T partial, K from registers
    f32x16 st = {};
#pragma unroll
    for (int cc = 0; cc < 16; ++cc) st = mfma32f8(kf[cc], qf8[cc], st);

    // kf prefetch (t+1) -- WAR after QKT; drains at end barrier
    if (t < 63) {
      const u8* kp = K4b + ((size_t)(t + 1) << 14) + koff;
#pragma unroll
      for (int cc = 0; cc < 16; ++cc) kf[cc] = *(const i64*)(kp + cc * 512);
    }

    // write partial(t) to parity buffer
    {
      float* sp = &Sxf[t & 1][w][l31][0];
#pragma unroll
      for (int g = 0; g < 4; ++g) {
        const int slot = (2 * g + hi) ^ (l31 & 7);
        f32x4 v = {st[4 * g + 0], st[4 * g + 1], st[4 * g + 2], st[4 * g + 3]};
        *(f32x4*)&sp[slot * 4] = v;
      }
    }

    // lagged: combine + softmax + PV for step t-1 (independent of everything above)
    if (t > 0) LAGGED((t - 1) & 1, vread);

    sprev = st;

    // single end-of-step drain + barrier
    asm volatile("s_waitcnt vmcnt(0) lgkmcnt(0)" ::: "memory");
    __builtin_amdgcn_s_barrier();

    vstage = (vstage == 2) ? 0 : vstage + 1;
    vread = (vread == 2) ? 0 : vread + 1;
  }

  // epilogue: lagged block for t=63 (parity 1, vread == 0 after loop)
  LAGGED(1, vread);

  // -------- finalize --------
  lsum += __shfl_xor(lsum, 32, 64);
  const float inv = 1.0f / lsum;
  const int bb = bh >> 3, h = bh & 7;
  const int tq = qt * 128 + pr * 32 + l31;
  u16* orow_p = Og + (size_t)(bb * 2048 + tq) * 4096 + h * 512;
#pragma unroll
  for (int blk = 0; blk < 8; ++blk) {
    const int dbase = whalf * 256 + blk * 32 + 4 * hi;
#pragma unroll
    for (int g = 0; g < 4; ++g) {
      u16x4 pk;
#pragma unroll
      for (int z = 0; z < 4; ++z) pk[z] = f2bf(acc[blk][4 * g + z] * inv);
      *(u16x4*)(orow_p + dbase + 8 * g) = pk;
    }
  }
#undef STAGE_V
#undef LAGGED
}

// ---------------- launcher ----------------
// Per-batch: Q 8 + K 8 + Vt 16 + Og 16 = 48 MB.  ws need = 24 + 48*BB:
// BB=4 -> 216 MB, BB=2 -> 120 MB, BB=1 -> 72 MB.

extern "C" void kernel_launch(void* const* d_in, const int* in_sizes, int n_in,
                              void* d_out, int out_size, void* d_ws, size_t ws_size,
                              hipStream_t stream) {
  const float* x = (const float*)d_in[0];
  const float* Wq = (const float*)d_in[1];
  const float* Wk = (const float*)d_in[2];
  const float* Wv = (const float*)d_in[3];
  const float* Wo = (const float*)d_in[4];
  const float* bo = (const float*)d_in[5];
  float* out = (float*)d_out;

  const size_t MB = 1ull << 20;
  int BB;
  if (ws_size >= 216 * MB) BB = 4;
  else if (ws_size >= 120 * MB) BB = 2;
  else BB = 1;

  char* ws = (char*)d_ws;
  u16* xb  = (u16*)(ws);
  u16* Wqp = (u16*)(ws + 8 * MB);
  u16* Wkp = (u16*)(ws + 12 * MB);
  u16* Wvp = (u16*)(ws + 16 * MB);
  u16* Wot = (u16*)(ws + 20 * MB);
  u8*  Qg  = (u8*)(ws + 24 * MB);
  u8*  Kg  = (u8*)(ws + (24 + 8 * (size_t)BB) * MB);
  u16* Vtg = (u16*)(ws + (24 + 16 * (size_t)BB) * MB);
  u16* Og  = (u16*)(ws + (24 + 32 * (size_t)BB) * MB);

  pack_x_kernel<<<dim3(4096), dim3(256), 0, stream>>>(x, xb);
  pack_wqkv_t<<<dim3(64, 8), dim3(256), 0, stream>>>(Wq, Wqp);
  pack_wqkv_t<<<dim3(64, 8), dim3(256), 0, stream>>>(Wk, Wkp);
  pack_wqkv_t<<<dim3(64, 8), dim3(256), 0, stream>>>(Wv, Wvp);
  pack_wo_t<<<dim3(64, 8), dim3(256), 0, stream>>>(Wo, Wot);

  const float qk_scale = 0.21022410381342865f;  // 1 / 512^0.25

  const int nchunk = 4 / BB;
  for (int c = 0; c < nchunk; ++c) {
    const u16* Ax = xb + (size_t)c * BB * 2048 * 512;
    gemm_bf16<0><<<dim3(32, BB * 16), dim3(256), 0, stream>>>(Ax, Wqp, (void*)Qg, nullptr, 512, qk_scale);
    gemm_bf16<3><<<dim3(32, BB * 16), dim3(256), 0, stream>>>(Ax, Wkp, (void*)Kg, nullptr, 512, qk_scale);
    gemm_bf16<1><<<dim3(32, BB * 16), dim3(256), 0, stream>>>(Ax, Wvp, (void*)Vtg, nullptr, 512, 1.0f);

    attn_kernel<<<dim3(16 * BB * 8), dim3(512), 0, stream>>>(Qg, Kg, Vtg, Og, BB);

    gemm_bf16<2><<<dim3(4, BB * 16), dim3(256), 0, stream>>>(
        Og, Wot, (void*)(out + (size_t)c * BB * 2048 * 512), bo, 4096, 1.0f);
  }
}

// Round 16
// 531.556 us; speedup vs baseline: 1.1106x; 1.1106x over previous
//
#include <hip/hip_runtime.h>

typedef unsigned short u16;
typedef unsigned char u8;
typedef unsigned int u32;
typedef long i64;
typedef __attribute__((ext_vector_type(8))) short bf16x8;
typedef __attribute__((ext_vector_type(4))) float f32x4;
typedef __attribute__((ext_vector_type(4))) u16 u16x4;

__device__ __forceinline__ u16 f2bf(float f) {
  u32 u = __builtin_bit_cast(u32, f);
  return (u16)((u + 0x7FFFu + ((u >> 16) & 1u)) >> 16);
}
__device__ __forceinline__ u8 f2fp8(float f) {
  int w = __builtin_amdgcn_cvt_pk_fp8_f32(f, 0.f, 0, false);
  return (u8)(w & 0xff);
}

__device__ __forceinline__ f32x4 mfma16(bf16x8 a, bf16x8 b, f32x4 c) {
  return __builtin_amdgcn_mfma_f32_16x16x32_bf16(a, b, c, 0, 0, 0);
}
__device__ __forceinline__ f32x4 mfma16f8(i64 a, i64 b, f32x4 c) {
  return __builtin_amdgcn_mfma_f32_16x16x32_fp8_fp8(a, b, c, 0, 0, 0);
}

__device__ __forceinline__ void gload16(const void* g, void* l) {
  __builtin_amdgcn_global_load_lds(
      (const __attribute__((address_space(1))) unsigned int*)g,
      (__attribute__((address_space(3))) unsigned int*)l, 16, 0, 0);
}

__device__ __forceinline__ u32 cvtpk(float lo, float hi) {
  u32 r;
  asm volatile("v_cvt_pk_bf16_f32 %0, %1, %2" : "=v"(r) : "v"(lo), "v"(hi));
  return r;
}

// ---------------- pack kernels ----------------

__global__ void pack_x_kernel(const float* __restrict__ x, u16* __restrict__ xb) {
  const int i = blockIdx.x * 256 + threadIdx.x;
  const float4 v = ((const float4*)x)[i];
  u16x4 o;
  o[0] = f2bf(v.x); o[1] = f2bf(v.y); o[2] = f2bf(v.z); o[3] = f2bf(v.w);
  ((u16x4*)xb)[i] = o;
}

// W: [512][4096] col = k*8+h  ->  Wp: [h*512+k][dd]  (tiled LDS transpose)
__global__ void pack_wqkv_t(const float* __restrict__ W, u16* __restrict__ Wp) {
  __shared__ u16 tile[64][72];
  const int t = threadIdx.x;
  const int c0 = blockIdx.x * 64, dd0 = blockIdx.y * 64;
#pragma unroll
  for (int s = 0; s < 4; ++s) {
    const int r = s * 16 + (t >> 4);
    const int q = (t & 15) * 4;
    const float4 v = *(const float4*)&W[(size_t)(dd0 + r) * 4096 + c0 + q];
    tile[r][q + 0] = f2bf(v.x); tile[r][q + 1] = f2bf(v.y);
    tile[r][q + 2] = f2bf(v.z); tile[r][q + 3] = f2bf(v.w);
  }
  __syncthreads();
#pragma unroll
  for (int s = 0; s < 4; ++s) {
    const int cl = s * 16 + (t >> 4);
    const int u = t & 15;
    const int cg = c0 + cl;
    const int orow = (cg & 7) * 512 + (cg >> 3);
    u16x4 o;
#pragma unroll
    for (int i = 0; i < 4; ++i) o[i] = tile[u * 4 + i][cl];
    *(u16x4*)&Wp[(size_t)orow * 512 + dd0 + u * 4] = o;
  }
}

// Wo: [4096][512] -> Wot: [n=512][k=4096]
__global__ void pack_wo_t(const float* __restrict__ W, u16* __restrict__ Wp) {
  __shared__ u16 tile[64][72];
  const int t = threadIdx.x;
  const int k0 = blockIdx.x * 64, n0 = blockIdx.y * 64;
#pragma unroll
  for (int s = 0; s < 4; ++s) {
    const int r = s * 16 + (t >> 4);
    const int q = (t & 15) * 4;
    const float4 v = *(const float4*)&W[(size_t)(k0 + r) * 512 + n0 + q];
    tile[r][q + 0] = f2bf(v.x); tile[r][q + 1] = f2bf(v.y);
    tile[r][q + 2] = f2bf(v.z); tile[r][q + 3] = f2bf(v.w);
  }
  __syncthreads();
#pragma unroll
  for (int s = 0; s < 4; ++s) {
    const int cl = s * 16 + (t >> 4);
    const int u = t & 15;
    u16x4 o;
#pragma unroll
    for (int i = 0; i < 4; ++i) o[i] = tile[u * 4 + i][cl];
    *(u16x4*)&Wp[(size_t)(n0 + cl) * 4096 + k0 + u * 4] = o;
  }
}

// ---------------- GEMM: C[M][N] = A[M][Kd] * B[N][Kd]^T ----------------
// MODE 0: fp8 -> [bh][t][d] (*scale)            (Q, K)
// MODE 1: bf16 transposed -> Vt [bh][d][t]      (V)
// MODE 2: fp32 + bias -> [row][512]             (out)

template <int MODE>
__global__ __launch_bounds__(256, 2) void gemm_bf16(
    const u16* __restrict__ A, const u16* __restrict__ B,
    void* __restrict__ Cout, const float* __restrict__ bias,
    int Kd, float scale) {
  __shared__ u16 Al[128 * 64];
  __shared__ u16 Bl[128 * 64];
  const int tid = threadIdx.x;
  const int lane = tid & 63;
  const int w = tid >> 6, wm = w >> 1, wn = w & 1;
  const int l15 = lane & 15, lg = lane >> 4;
  const int m0 = blockIdx.y * 128, n0 = blockIdx.x * 128;

  f32x4 acc[4][4];
  const f32x4 zero = {0.f, 0.f, 0.f, 0.f};
#pragma unroll
  for (int i = 0; i < 4; ++i)
#pragma unroll
    for (int j = 0; j < 4; ++j) acc[i][j] = zero;

  const int nk = Kd >> 6;
  for (int kt = 0; kt < nk; ++kt) {
    __syncthreads();
    const int k0 = kt << 6;
#pragma unroll
    for (int s = 0; s < 4; ++s) {
      const int chunk = s * 256 + tid;
      const int row = chunk >> 3, c = chunk & 7;
      const int cs = c ^ (row & 7);
      gload16(A + (size_t)(m0 + row) * Kd + k0 + cs * 8, &Al[chunk * 8]);
    }
#pragma unroll
    for (int s = 0; s < 4; ++s) {
      const int chunk = s * 256 + tid;
      const int row = chunk >> 3, c = chunk & 7;
      const int cs = c ^ (row & 7);
      gload16(B + (size_t)(n0 + row) * Kd + k0 + cs * 8, &Bl[chunk * 8]);
    }
    __syncthreads();
#pragma unroll
    for (int kk = 0; kk < 2; ++kk) {
      bf16x8 af[4], bfr[4];
      const int ch = kk * 4 + lg;
#pragma unroll
      for (int i = 0; i < 4; ++i) {
        const int ar = wm * 64 + i * 16 + l15;
        af[i] = *(const bf16x8*)&Al[ar * 64 + ((ch ^ (ar & 7)) * 8)];
        const int br = wn * 64 + i * 16 + l15;
        bfr[i] = *(const bf16x8*)&Bl[br * 64 + ((ch ^ (br & 7)) * 8)];
      }
#pragma unroll
      for (int i = 0; i < 4; ++i)
#pragma unroll
        for (int j = 0; j < 4; ++j)
          acc[i][j] = mfma16(af[i], bfr[j], acc[i][j]);
    }
  }

#pragma unroll
  for (int i = 0; i < 4; ++i) {
    const int gr0 = m0 + wm * 64 + i * 16 + lg * 4;
#pragma unroll
    for (int j = 0; j < 4; ++j) {
      const int gc = n0 + wn * 64 + j * 16 + l15;
      if constexpr (MODE == 0) {
        u8* O = (u8*)Cout;
        const int h = gc >> 9, d = gc & 511;
#pragma unroll
        for (int r = 0; r < 4; ++r) {
          const int grr = gr0 + r;
          const int bb = grr >> 11, t = grr & 2047;
          O[((size_t)((bb * 8 + h) * 2048 + t) << 9) + d] = f2fp8(acc[i][j][r] * scale);
        }
      } else if constexpr (MODE == 1) {
        u16* O = (u16*)Cout;
        const int h = gc >> 9, d = gc & 511;
        const int bb = gr0 >> 11, t = gr0 & 2047;
        u16x4 pk;
#pragma unroll
        for (int r = 0; r < 4; ++r) pk[r] = f2bf(acc[i][j][r]);
        *(u16x4*)&O[((size_t)((bb * 8 + h) * 512 + d) << 11) + t] = pk;
      } else {
        float* O = (float*)Cout;
        const float bv = bias[gc];
#pragma unroll
        for (int r = 0; r < 4; ++r)
          O[(size_t)(gr0 + r) * 512 + gc] = acc[i][j][r] + bv;
      }
    }
  }
}

// ---------------- flash attention v16: kv-split, full-k QKT, 16x16 MFMA ----------------
// Q,K fp8: [bh][2048][512]B; Vt bf16: [bh][512][2048]; Og bf16: [bb*2048+t][h*512+d]
// block = 8 waves = 4 pairs; pair owns 32 q rows (128 q/block).
// Wave (pr,whalf): kv rows whalf*16..+15 of each 32-kv tile (FULL k=512 QKT -> complete
// logits) and d-half whalf*256..+255 for PV (all 32 kv, P shared via bf16 LDS).
// KV block 32, 64 steps. LDS = K8 dbuf 2x16K + Vt dbuf 2x32K + P 8K + Lsum 1K = 105.5K.
// Pacing = v12 (proven): stage K+V(t+1) at step START, mid lgkm-barrier (P visible),
// single vmcnt(0)+lgkm(0) barrier at step END. Constant-m softmax (r14-verified).

__global__ __launch_bounds__(512, 2) void attn_kernel(
    const u8* __restrict__ Qg, const u8* __restrict__ Kg,
    const u16* __restrict__ Vtg, u16* __restrict__ Og, int nbh_pxcd) {
  __shared__ u8 K8[2][32 * 512];       // [buf][kv][k]B  16B-pos swz: p ^ ((kv&15)<<1)
  __shared__ u16 Vt_lds[2][512 * 32];  // [buf][d][kv]   16B-pos swz: p ^ ((d>>1)&3)
  __shared__ u16 P_lds[4][2][16][32];  // [pair][qtile][q][kv] bf16
  __shared__ float Lsum[8][2][16];     // per-wave partial row sums (finalize)

  const int tid = threadIdx.x;
  const int lane = tid & 63;
  const int w = tid >> 6;
  const int pr = w >> 1, whalf = w & 1;
  const int l15 = lane & 15, lg = lane >> 4;

  const int bid = blockIdx.x;
  const int x8 = bid & 7, rest = bid >> 3;
  const int qt = rest & 15;
  const int bh = x8 * nbh_pxcd + (rest >> 4);

  const u8* Qb = Qg + (size_t)bh * 2048 * 512;
  const u8* Kb = Kg + (size_t)bh * 2048 * 512;
  const u16* Vb = Vtg + (size_t)bh * 2048 * 512;

  // Q fp8 fragments, full k: qf8[qtile][cc] covers k = cc*32 + lg*8 .. +7
  i64 qf8[2][16];
#pragma unroll
  for (int qtile = 0; qtile < 2; ++qtile) {
    const int qrow = qt * 128 + pr * 32 + qtile * 16 + l15;
    const u8* qp = Qb + (size_t)qrow * 512 + lg * 8;
#pragma unroll
    for (int cc = 0; cc < 16; ++cc) qf8[qtile][cc] = *(const i64*)(qp + cc * 32);
  }

  f32x4 acc[2][16];
#pragma unroll
  for (int i = 0; i < 2; ++i)
#pragma unroll
    for (int j = 0; j < 16; ++j) acc[i][j] = {};
  float lsum0 = 0.f, lsum1 = 0.f;

  // K row this wave reads as A-operand: kv = whalf*16 + l15
  const int krow = whalf * 16 + l15;
  const int kswz = (krow & 15) << 1;

#define STAGE_K8(tile, buf)                                                   \
  {                                                                           \
    _Pragma("unroll") for (int s_ = 0; s_ < 2; ++s_) {                        \
      const int ch = s_ * 512 + tid;                                          \
      const int row = ch >> 5, p_ = ch & 31;                                  \
      const int ps = p_ ^ ((row & 15) << 1);                                  \
      gload16(Kb + (size_t)((tile) * 32 + row) * 512 + ps * 16,               \
              &K8[buf][ch * 16]);                                             \
    }                                                                         \
  }
#define STAGE_V(tile, buf)                                                    \
  {                                                                           \
    _Pragma("unroll") for (int s_ = 0; s_ < 4; ++s_) {                        \
      const int chunk = s_ * 512 + tid;                                       \
      const int row = chunk >> 2, c_ = chunk & 3;                             \
      const int cs = c_ ^ ((row >> 1) & 3);                                   \
      gload16(Vb + (size_t)row * 2048 + (tile) * 32 + cs * 8,                 \
              &Vt_lds[buf][chunk * 8]);                                       \
    }                                                                         \
  }

  // -------- prologue: stage tile 0 --------
  STAGE_K8(0, 0);
  STAGE_V(0, 0);
  asm volatile("s_waitcnt vmcnt(0)" ::: "memory");
  __builtin_amdgcn_s_barrier();

  for (int t = 0; t < 64; ++t) {
    const int cur = t & 1;

    // stage tiles(t+1) at step START (in flight across whole step; convoy pacing)
    if (t < 63) {
      STAGE_K8(t + 1, cur ^ 1);
      STAGE_V(t + 1, cur ^ 1);
    }

    // QKT(t): complete logits S[kv 16][q 32], full k=512; 4 independent 8-chains
    f32x4 s0a = {}, s0b = {}, s1a = {}, s1b = {};
    {
      const u8* kbase = &K8[cur][krow * 512 + (lg & 1) * 8];
      const int phalf = lg >> 1;
#pragma unroll
      for (int cc = 0; cc < 8; ++cc) {
        const int p = (cc * 2 + phalf) ^ kswz;
        i64 kf = *(const i64*)(kbase + p * 16);
        s0a = mfma16f8(kf, qf8[0][cc], s0a);
        s1a = mfma16f8(kf, qf8[1][cc], s1a);
      }
#pragma unroll
      for (int cc = 8; cc < 16; ++cc) {
        const int p = (cc * 2 + phalf) ^ kswz;
        i64 kf = *(const i64*)(kbase + p * 16);
        s0b = mfma16f8(kf, qf8[0][cc], s0b);
        s1b = mfma16f8(kf, qf8[1][cc], s1b);
      }
    }
    f32x4 s0, s1;
#pragma unroll
    for (int r = 0; r < 4; ++r) {
      s0[r] = s0a[r] + s0b[r];
      s1[r] = s1a[r] + s1b[r];
    }

    // constant-m softmax: p = exp(s); per-lane partial row sums
#pragma unroll
    for (int r = 0; r < 4; ++r) {
      s0[r] = __expf(s0[r]);
      lsum0 += s0[r];
      s1[r] = __expf(s1[r]);
      lsum1 += s1[r];
    }

    // write P bf16: lane holds P[kv = whalf*16 + lg*4 + r][q = qtile*16 + l15]
    {
      const int kvbase = whalf * 16 + lg * 4;
      u16x4 pk0, pk1;
      u32 a0 = cvtpk(s0[0], s0[1]), a1 = cvtpk(s0[2], s0[3]);
      u32 b0 = cvtpk(s1[0], s1[1]), b1 = cvtpk(s1[2], s1[3]);
      pk0 = __builtin_bit_cast(u16x4, ((unsigned long long)a1 << 32) | a0);
      pk1 = __builtin_bit_cast(u16x4, ((unsigned long long)b1 << 32) | b0);
      *(u16x4*)&P_lds[pr][0][l15][kvbase] = pk0;
      *(u16x4*)&P_lds[pr][1][l15][kvbase] = pk1;
    }
    asm volatile("s_waitcnt lgkmcnt(0)" ::: "memory");
    __builtin_amdgcn_s_barrier();  // mid: P visible pair-wide

    // PV(t): O^T[d 16-tiles][q 16x2] over all 32 kv; A=V rows, B=P
    {
      bf16x8 pfr[2];
      pfr[0] = *(const bf16x8*)&P_lds[pr][0][l15][lg * 8];
      pfr[1] = *(const bf16x8*)&P_lds[pr][1][l15][lg * 8];
#pragma unroll
      for (int dtile = 0; dtile < 16; ++dtile) {
        const int drow = whalf * 256 + dtile * 16 + l15;
        const int pos = lg ^ ((drow >> 1) & 3);
        bf16x8 vf = *(const bf16x8*)&Vt_lds[cur][drow * 32 + pos * 8];
        acc[0][dtile] = mfma16(vf, pfr[0], acc[0][dtile]);
        acc[1][dtile] = mfma16(vf, pfr[1], acc[1][dtile]);
      }
    }

    // end of step: staging complete; P/V/K reads retired before next overwrite
    asm volatile("s_waitcnt vmcnt(0) lgkmcnt(0)" ::: "memory");
    __builtin_amdgcn_s_barrier();
  }

  // -------- finalize: reduce lsum across lg groups, then across pair --------
  lsum0 += __shfl_xor(lsum0, 16, 64);
  lsum0 += __shfl_xor(lsum0, 32, 64);
  lsum1 += __shfl_xor(lsum1, 16, 64);
  lsum1 += __shfl_xor(lsum1, 32, 64);
  if (lane < 16) {
    Lsum[w][0][l15] = lsum0;
    Lsum[w][1][l15] = lsum1;
  }
  __syncthreads();
  const float inv0 = 1.0f / (Lsum[w][0][l15] + Lsum[w ^ 1][0][l15]);
  const float inv1 = 1.0f / (Lsum[w][1][l15] + Lsum[w ^ 1][1][l15]);

  const int bb = bh >> 3, h = bh & 7;
#pragma unroll
  for (int qtile = 0; qtile < 2; ++qtile) {
    const float inv = qtile ? inv1 : inv0;
    const int q = qt * 128 + pr * 32 + qtile * 16 + l15;
    u16* orow_p = Og + (size_t)(bb * 2048 + q) * 4096 + h * 512 + whalf * 256;
#pragma unroll
    for (int dtile = 0; dtile < 16; ++dtile) {
      u16x4 pk;
#pragma unroll
      for (int r = 0; r < 4; ++r) pk[r] = f2bf(acc[qtile][dtile][r] * inv);
      *(u16x4*)(orow_p + dtile * 16 + lg * 4) = pk;
    }
  }
#undef STAGE_K8
#undef STAGE_V
}

// ---------------- launcher ----------------
// Per-batch: Q 8 + K 8 + Vt 16 + Og 16 = 48 MB.  ws need = 24 + 48*BB:
// BB=4 -> 216 MB, BB=2 -> 120 MB, BB=1 -> 72 MB.

extern "C" void kernel_launch(void* const* d_in, const int* in_sizes, int n_in,
                              void* d_out, int out_size, void* d_ws, size_t ws_size,
                              hipStream_t stream) {
  const float* x = (const float*)d_in[0];
  const float* Wq = (const float*)d_in[1];
  const float* Wk = (const float*)d_in[2];
  const float* Wv = (const float*)d_in[3];
  const float* Wo = (const float*)d_in[4];
  const float* bo = (const float*)d_in[5];
  float* out = (float*)d_out;

  const size_t MB = 1ull << 20;
  int BB;
  if (ws_size >= 216 * MB) BB = 4;
  else if (ws_size >= 120 * MB) BB = 2;
  else BB = 1;

  char* ws = (char*)d_ws;
  u16* xb  = (u16*)(ws);
  u16* Wqp = (u16*)(ws + 8 * MB);
  u16* Wkp = (u16*)(ws + 12 * MB);
  u16* Wvp = (u16*)(ws + 16 * MB);
  u16* Wot = (u16*)(ws + 20 * MB);
  u8*  Qg  = (u8*)(ws + 24 * MB);
  u8*  Kg  = (u8*)(ws + (24 + 8 * (size_t)BB) * MB);
  u16* Vtg = (u16*)(ws + (24 + 16 * (size_t)BB) * MB);
  u16* Og  = (u16*)(ws + (24 + 32 * (size_t)BB) * MB);

  pack_x_kernel<<<dim3(4096), dim3(256), 0, stream>>>(x, xb);
  pack_wqkv_t<<<dim3(64, 8), dim3(256), 0, stream>>>(Wq, Wqp);
  pack_wqkv_t<<<dim3(64, 8), dim3(256), 0, stream>>>(Wk, Wkp);
  pack_wqkv_t<<<dim3(64, 8), dim3(256), 0, stream>>>(Wv, Wvp);
  pack_wo_t<<<dim3(64, 8), dim3(256), 0, stream>>>(Wo, Wot);

  const float qk_scale = 0.21022410381342865f;  // 1 / 512^0.25

  const int nchunk = 4 / BB;
  for (int c = 0; c < nchunk; ++c) {
    const u16* Ax = xb + (size_t)c * BB * 2048 * 512;
    gemm_bf16<0><<<dim3(32, BB * 16), dim3(256), 0, stream>>>(Ax, Wqp, (void*)Qg, nullptr, 512, qk_scale);
    gemm_bf16<0><<<dim3(32, BB * 16), dim3(256), 0, stream>>>(Ax, Wkp, (void*)Kg, nullptr, 512, qk_scale);
    gemm_bf16<1><<<dim3(32, BB * 16), dim3(256), 0, stream>>>(Ax, Wvp, (void*)Vtg, nullptr, 512, 1.0f);

    attn_kernel<<<dim3(16 * BB * 8), dim3(512), 0, stream>>>(Qg, Kg, Vtg, Og, BB);

    gemm_bf16<2><<<dim3(4, BB * 16), dim3(256), 0, stream>>>(
        Og, Wot, (void*)(out + (size_t)c * BB * 2048 * 512), bo, 4096, 1.0f);
  }
}

// Round 17
// 524.011 us; speedup vs baseline: 1.1266x; 1.0144x over previous
//
#include <hip/hip_runtime.h>

typedef unsigned short u16;
typedef unsigned char u8;
typedef unsigned int u32;
typedef long i64;
typedef __attribute__((ext_vector_type(8))) short bf16x8;
typedef __attribute__((ext_vector_type(4))) float f32x4;
typedef __attribute__((ext_vector_type(4))) u16 u16x4;

__device__ __forceinline__ u16 f2bf(float f) {
  u32 u = __builtin_bit_cast(u32, f);
  return (u16)((u + 0x7FFFu + ((u >> 16) & 1u)) >> 16);
}
__device__ __forceinline__ u8 f2fp8(float f) {
  int w = __builtin_amdgcn_cvt_pk_fp8_f32(f, 0.f, 0, false);
  return (u8)(w & 0xff);
}

__device__ __forceinline__ f32x4 mfma16(bf16x8 a, bf16x8 b, f32x4 c) {
  return __builtin_amdgcn_mfma_f32_16x16x32_bf16(a, b, c, 0, 0, 0);
}
__device__ __forceinline__ f32x4 mfma16f8(i64 a, i64 b, f32x4 c) {
  return __builtin_amdgcn_mfma_f32_16x16x32_fp8_fp8(a, b, c, 0, 0, 0);
}

__device__ __forceinline__ void gload16(const void* g, void* l) {
  __builtin_amdgcn_global_load_lds(
      (const __attribute__((address_space(1))) unsigned int*)g,
      (__attribute__((address_space(3))) unsigned int*)l, 16, 0, 0);
}

__device__ __forceinline__ u32 cvtpk(float lo, float hi) {
  u32 r;
  asm volatile("v_cvt_pk_bf16_f32 %0, %1, %2" : "=v"(r) : "v"(lo), "v"(hi));
  return r;
}

// ---------------- pack kernels ----------------

__global__ void pack_x_kernel(const float* __restrict__ x, u16* __restrict__ xb) {
  const int i = blockIdx.x * 256 + threadIdx.x;
  const float4 v = ((const float4*)x)[i];
  u16x4 o;
  o[0] = f2bf(v.x); o[1] = f2bf(v.y); o[2] = f2bf(v.z); o[3] = f2bf(v.w);
  ((u16x4*)xb)[i] = o;
}

// W: [512][4096] col = k*8+h  ->  Wp: [h*512+k][dd]  (tiled LDS transpose)
__global__ void pack_wqkv_t(const float* __restrict__ W, u16* __restrict__ Wp) {
  __shared__ u16 tile[64][72];
  const int t = threadIdx.x;
  const int c0 = blockIdx.x * 64, dd0 = blockIdx.y * 64;
#pragma unroll
  for (int s = 0; s < 4; ++s) {
    const int r = s * 16 + (t >> 4);
    const int q = (t & 15) * 4;
    const float4 v = *(const float4*)&W[(size_t)(dd0 + r) * 4096 + c0 + q];
    tile[r][q + 0] = f2bf(v.x); tile[r][q + 1] = f2bf(v.y);
    tile[r][q + 2] = f2bf(v.z); tile[r][q + 3] = f2bf(v.w);
  }
  __syncthreads();
#pragma unroll
  for (int s = 0; s < 4; ++s) {
    const int cl = s * 16 + (t >> 4);
    const int u = t & 15;
    const int cg = c0 + cl;
    const int orow = (cg & 7) * 512 + (cg >> 3);
    u16x4 o;
#pragma unroll
    for (int i = 0; i < 4; ++i) o[i] = tile[u * 4 + i][cl];
    *(u16x4*)&Wp[(size_t)orow * 512 + dd0 + u * 4] = o;
  }
}

// Wo: [4096][512] -> Wot: [n=512][k=4096]
__global__ void pack_wo_t(const float* __restrict__ W, u16* __restrict__ Wp) {
  __shared__ u16 tile[64][72];
  const int t = threadIdx.x;
  const int k0 = blockIdx.x * 64, n0 = blockIdx.y * 64;
#pragma unroll
  for (int s = 0; s < 4; ++s) {
    const int r = s * 16 + (t >> 4);
    const int q = (t & 15) * 4;
    const float4 v = *(const float4*)&W[(size_t)(k0 + r) * 512 + n0 + q];
    tile[r][q + 0] = f2bf(v.x); tile[r][q + 1] = f2bf(v.y);
    tile[r][q + 2] = f2bf(v.z); tile[r][q + 3] = f2bf(v.w);
  }
  __syncthreads();
#pragma unroll
  for (int s = 0; s < 4; ++s) {
    const int cl = s * 16 + (t >> 4);
    const int u = t & 15;
    u16x4 o;
#pragma unroll
    for (int i = 0; i < 4; ++i) o[i] = tile[u * 4 + i][cl];
    *(u16x4*)&Wp[(size_t)(n0 + cl) * 4096 + k0 + u * 4] = o;
  }
}

// ---------------- GEMM: C[M][N] = A[M][Kd] * B[N][Kd]^T ----------------
// MODE 0: fp8 -> [bh][t][d] (*scale)            (Q, K)   BN=128
// MODE 1: bf16 transposed -> Vt [bh][d][t]      (V)      BN=128
// MODE 2: fp32 + bias -> [row][512]             (out)    BN=64 (2 blocks/CU)
// BN: B-tile rows. Wave layout 2M x 2N; per-wave N = BN/2; JT = BN/32 j-tiles.

template <int MODE, int BN>
__global__ __launch_bounds__(256, 2) void gemm_bf16(
    const u16* __restrict__ A, const u16* __restrict__ B,
    void* __restrict__ Cout, const float* __restrict__ bias,
    int Kd, float scale) {
  constexpr int JT = BN / 32;
  __shared__ u16 Al[128 * 64];
  __shared__ u16 Bl[BN * 64];
  const int tid = threadIdx.x;
  const int lane = tid & 63;
  const int w = tid >> 6, wm = w >> 1, wn = w & 1;
  const int l15 = lane & 15, lg = lane >> 4;
  const int m0 = blockIdx.y * 128, n0 = blockIdx.x * BN;

  f32x4 acc[4][JT];
#pragma unroll
  for (int i = 0; i < 4; ++i)
#pragma unroll
    for (int j = 0; j < JT; ++j) acc[i][j] = {};

  const int nk = Kd >> 6;
  for (int kt = 0; kt < nk; ++kt) {
    __syncthreads();
    const int k0 = kt << 6;
#pragma unroll
    for (int s = 0; s < 4; ++s) {
      const int chunk = s * 256 + tid;
      const int row = chunk >> 3, c = chunk & 7;
      const int cs = c ^ (row & 7);
      gload16(A + (size_t)(m0 + row) * Kd + k0 + cs * 8, &Al[chunk * 8]);
    }
#pragma unroll
    for (int s = 0; s < BN / 32; ++s) {
      const int chunk = s * 256 + tid;
      const int row = chunk >> 3, c = chunk & 7;
      const int cs = c ^ (row & 7);
      gload16(B + (size_t)(n0 + row) * Kd + k0 + cs * 8, &Bl[chunk * 8]);
    }
    __syncthreads();
#pragma unroll
    for (int kk = 0; kk < 2; ++kk) {
      bf16x8 af[4], bfr[JT];
      const int ch = kk * 4 + lg;
#pragma unroll
      for (int i = 0; i < 4; ++i) {
        const int ar = wm * 64 + i * 16 + l15;
        af[i] = *(const bf16x8*)&Al[ar * 64 + ((ch ^ (ar & 7)) * 8)];
      }
#pragma unroll
      for (int j = 0; j < JT; ++j) {
        const int br = wn * (BN / 2) + j * 16 + l15;
        bfr[j] = *(const bf16x8*)&Bl[br * 64 + ((ch ^ (br & 7)) * 8)];
      }
#pragma unroll
      for (int i = 0; i < 4; ++i)
#pragma unroll
        for (int j = 0; j < JT; ++j)
          acc[i][j] = mfma16(af[i], bfr[j], acc[i][j]);
    }
  }

#pragma unroll
  for (int i = 0; i < 4; ++i) {
    const int gr0 = m0 + wm * 64 + i * 16 + lg * 4;
#pragma unroll
    for (int j = 0; j < JT; ++j) {
      const int gc = n0 + wn * (BN / 2) + j * 16 + l15;
      if constexpr (MODE == 0) {
        u8* O = (u8*)Cout;
        const int h = gc >> 9, d = gc & 511;
#pragma unroll
        for (int r = 0; r < 4; ++r) {
          const int grr = gr0 + r;
          const int bb = grr >> 11, t = grr & 2047;
          O[((size_t)((bb * 8 + h) * 2048 + t) << 9) + d] = f2fp8(acc[i][j][r] * scale);
        }
      } else if constexpr (MODE == 1) {
        u16* O = (u16*)Cout;
        const int h = gc >> 9, d = gc & 511;
        const int bb = gr0 >> 11, t = gr0 & 2047;
        u16x4 pk;
#pragma unroll
        for (int r = 0; r < 4; ++r) pk[r] = f2bf(acc[i][j][r]);
        *(u16x4*)&O[((size_t)((bb * 8 + h) * 512 + d) << 11) + t] = pk;
      } else {
        float* O = (float*)Cout;
        const float bv = bias[gc];
#pragma unroll
        for (int r = 0; r < 4; ++r)
          O[(size_t)(gr0 + r) * 512 + gc] = acc[i][j][r] + bv;
      }
    }
  }
}

// ---------------- flash attention v17: kv-split + PV-lag, single barrier/step ----------------
// Q,K fp8: [bh][2048][512]B; Vt bf16: [bh][512][2048]; Og bf16: [bb*2048+t][h*512+d]
// block = 8 waves = 4 pairs; pair owns 32 q rows (128 q/block).
// Wave (pr,whalf): QKT for kv rows whalf*16..+15 (full k=512 -> complete logits);
// PV for d-half whalf*256..+255 over all 32 kv of the LAGGED tile (t-1).
// KV block 32, 64 steps. LDS = K8 dbuf 32K + V3 tribuf 96K + P parity-dbuf 16K + L 1K.
// ONE barrier per step (end: vmcnt(0)+lgkm(0)). Ledger:
//   P(t) write parity t&1; PV(t-1) reads parity (t-1)&1 (disjoint); same-parity rewrite
//   separated by 2 barriers. V(x): staged t=x-1 -> buf x%3, read t=x+1, rewritten t=x+2.
//   K dbuf: read t&1, staged (t+1)&1. Constant-m softmax (r14-verified).

__global__ __launch_bounds__(512, 2) void attn_kernel(
    const u8* __restrict__ Qg, const u8* __restrict__ Kg,
    const u16* __restrict__ Vtg, u16* __restrict__ Og, int nbh_pxcd) {
  __shared__ u8 K8[2][32 * 512];          // [buf][kv][k]B  16B-pos swz: p ^ ((kv&15)<<1)
  __shared__ u16 V3[3][512 * 32];         // [buf][d][kv]   8-u16 chunk swz: c ^ ((d>>1)&3)
  __shared__ u16 P_lds[2][4][2][16][32];  // [parity][pair][qtile][q][kv] bf16
  __shared__ float Lsum[8][2][16];

  const int tid = threadIdx.x;
  const int lane = tid & 63;
  const int w = tid >> 6;
  const int pr = w >> 1, whalf = w & 1;
  const int l15 = lane & 15, lg = lane >> 4;

  const int bid = blockIdx.x;
  const int x8 = bid & 7, rest = bid >> 3;
  const int qt = rest & 15;
  const int bh = x8 * nbh_pxcd + (rest >> 4);

  const u8* Qb = Qg + (size_t)bh * 2048 * 512;
  const u8* Kb = Kg + (size_t)bh * 2048 * 512;
  const u16* Vb = Vtg + (size_t)bh * 2048 * 512;

  // Q fp8 fragments, full k: qf8[qtile][cc] covers k = cc*32 + lg*8 .. +7
  i64 qf8[2][16];
#pragma unroll
  for (int qtile = 0; qtile < 2; ++qtile) {
    const int qrow = qt * 128 + pr * 32 + qtile * 16 + l15;
    const u8* qp = Qb + (size_t)qrow * 512 + lg * 8;
#pragma unroll
    for (int cc = 0; cc < 16; ++cc) qf8[qtile][cc] = *(const i64*)(qp + cc * 32);
  }

  f32x4 acc[2][16];
#pragma unroll
  for (int i = 0; i < 2; ++i)
#pragma unroll
    for (int j = 0; j < 16; ++j) acc[i][j] = {};
  float lsum0 = 0.f, lsum1 = 0.f;

  const int krow = whalf * 16 + l15;
  const int kswz = (krow & 15) << 1;

#define STAGE_K8(tile, buf)                                                   \
  {                                                                           \
    _Pragma("unroll") for (int s_ = 0; s_ < 2; ++s_) {                        \
      const int ch = s_ * 512 + tid;                                          \
      const int row = ch >> 5, p_ = ch & 31;                                  \
      const int ps = p_ ^ ((row & 15) << 1);                                  \
      gload16(Kb + (size_t)((tile) * 32 + row) * 512 + ps * 16,               \
              &K8[buf][ch * 16]);                                             \
    }                                                                         \
  }
#define STAGE_V(tile, buf)                                                    \
  {                                                                           \
    _Pragma("unroll") for (int s_ = 0; s_ < 4; ++s_) {                        \
      const int chunk = s_ * 512 + tid;                                       \
      const int row = chunk >> 2, c_ = chunk & 3;                             \
      const int cs = c_ ^ ((row >> 1) & 3);                                   \
      gload16(Vb + (size_t)row * 2048 + (tile) * 32 + cs * 8,                 \
              &V3[buf][chunk * 8]);                                           \
    }                                                                         \
  }

  // PV for lagged tile: reads P_lds[par][pr][*] (full 32 kv) and V3[vbuf]
#define PV_LAG(par, vbuf)                                                     \
  {                                                                           \
    bf16x8 pfr0 = *(const bf16x8*)&P_lds[par][pr][0][l15][lg * 8];            \
    bf16x8 pfr1 = *(const bf16x8*)&P_lds[par][pr][1][l15][lg * 8];            \
    _Pragma("unroll") for (int dtile = 0; dtile < 16; ++dtile) {              \
      const int drow = whalf * 256 + dtile * 16 + l15;                        \
      const int pos = lg ^ ((drow >> 1) & 3);                                 \
      bf16x8 vf = *(const bf16x8*)&V3[vbuf][drow * 32 + pos * 8];             \
      acc[0][dtile] = mfma16(vf, pfr0, acc[0][dtile]);                        \
      acc[1][dtile] = mfma16(vf, pfr1, acc[1][dtile]);                        \
    }                                                                         \
  }

  // -------- prologue: stage tile 0 --------
  STAGE_K8(0, 0);
  STAGE_V(0, 0);
  asm volatile("s_waitcnt vmcnt(0)" ::: "memory");
  __builtin_amdgcn_s_barrier();

  int vstage = 1;  // (t+1)%3
  int vread = 2;   // (t-1)%3

  for (int t = 0; t < 64; ++t) {
    const int cur = t & 1;

    // stage tiles(t+1) at step START (in flight across whole step; convoy pacing)
    if (t < 63) {
      STAGE_K8(t + 1, cur ^ 1);
      STAGE_V(t + 1, vstage);
    }

    // QKT(t): complete logits S[kv 16][q 32], full k; 4 independent 8-chains
    f32x4 s0a = {}, s0b = {}, s1a = {}, s1b = {};
    {
      const u8* kbase = &K8[cur][krow * 512 + (lg & 1) * 8];
      const int phalf = lg >> 1;
#pragma unroll
      for (int cc = 0; cc < 8; ++cc) {
        const int p = (cc * 2 + phalf) ^ kswz;
        i64 kf = *(const i64*)(kbase + p * 16);
        s0a = mfma16f8(kf, qf8[0][cc], s0a);
        s1a = mfma16f8(kf, qf8[1][cc], s1a);
      }
#pragma unroll
      for (int cc = 8; cc < 16; ++cc) {
        const int p = (cc * 2 + phalf) ^ kswz;
        i64 kf = *(const i64*)(kbase + p * 16);
        s0b = mfma16f8(kf, qf8[0][cc], s0b);
        s1b = mfma16f8(kf, qf8[1][cc], s1b);
      }
    }
    f32x4 s0, s1;
#pragma unroll
    for (int r = 0; r < 4; ++r) {
      s0[r] = __expf(s0a[r] + s0b[r]);
      lsum0 += s0[r];
      s1[r] = __expf(s1a[r] + s1b[r]);
      lsum1 += s1[r];
    }

    // write P(t) bf16 to parity buffer t&1
    {
      const int kvbase = whalf * 16 + lg * 4;
      u32 a0 = cvtpk(s0[0], s0[1]), a1 = cvtpk(s0[2], s0[3]);
      u32 b0 = cvtpk(s1[0], s1[1]), b1 = cvtpk(s1[2], s1[3]);
      u16x4 pk0 = __builtin_bit_cast(u16x4, ((unsigned long long)a1 << 32) | a0);
      u16x4 pk1 = __builtin_bit_cast(u16x4, ((unsigned long long)b1 << 32) | b0);
      *(u16x4*)&P_lds[cur][pr][0][l15][kvbase] = pk0;
      *(u16x4*)&P_lds[cur][pr][1][l15][kvbase] = pk1;
    }

    // PV for lagged tile (t-1): P parity (t-1)&1, V buf (t-1)%3
    if (t > 0) PV_LAG(cur ^ 1, vread);

    // single end-of-step drain + barrier
    asm volatile("s_waitcnt vmcnt(0) lgkmcnt(0)" ::: "memory");
    __builtin_amdgcn_s_barrier();

    vstage = (vstage == 2) ? 0 : vstage + 1;
    vread = (vread == 2) ? 0 : vread + 1;
  }

  // epilogue: PV(63): parity 1, V buf 63%3 == 0 (vread after loop == 0)
  PV_LAG(1, vread);

  // -------- finalize: reduce lsum across lg groups, then across pair --------
  lsum0 += __shfl_xor(lsum0, 16, 64);
  lsum0 += __shfl_xor(lsum0, 32, 64);
  lsum1 += __shfl_xor(lsum1, 16, 64);
  lsum1 += __shfl_xor(lsum1, 32, 64);
  if (lane < 16) {
    Lsum[w][0][l15] = lsum0;
    Lsum[w][1][l15] = lsum1;
  }
  __syncthreads();
  const float inv0 = 1.0f / (Lsum[w][0][l15] + Lsum[w ^ 1][0][l15]);
  const float inv1 = 1.0f / (Lsum[w][1][l15] + Lsum[w ^ 1][1][l15]);

  const int bb = bh >> 3, h = bh & 7;
#pragma unroll
  for (int qtile = 0; qtile < 2; ++qtile) {
    const float inv = qtile ? inv1 : inv0;
    const int q = qt * 128 + pr * 32 + qtile * 16 + l15;
    u16* orow_p = Og + (size_t)(bb * 2048 + q) * 4096 + h * 512 + whalf * 256;
#pragma unroll
    for (int dtile = 0; dtile < 16; ++dtile) {
      u16x4 pk;
#pragma unroll
      for (int r = 0; r < 4; ++r) pk[r] = f2bf(acc[qtile][dtile][r] * inv);
      *(u16x4*)(orow_p + dtile * 16 + lg * 4) = pk;
    }
  }
#undef STAGE_K8
#undef STAGE_V
#undef PV_LAG
}

// ---------------- launcher ----------------
// Per-batch: Q 8 + K 8 + Vt 16 + Og 16 = 48 MB.  ws need = 24 + 48*BB:
// BB=4 -> 216 MB, BB=2 -> 120 MB, BB=1 -> 72 MB.

extern "C" void kernel_launch(void* const* d_in, const int* in_sizes, int n_in,
                              void* d_out, int out_size, void* d_ws, size_t ws_size,
                              hipStream_t stream) {
  const float* x = (const float*)d_in[0];
  const float* Wq = (const float*)d_in[1];
  const float* Wk = (const float*)d_in[2];
  const float* Wv = (const float*)d_in[3];
  const float* Wo = (const float*)d_in[4];
  const float* bo = (const float*)d_in[5];
  float* out = (float*)d_out;

  const size_t MB = 1ull << 20;
  int BB;
  if (ws_size >= 216 * MB) BB = 4;
  else if (ws_size >= 120 * MB) BB = 2;
  else BB = 1;

  char* ws = (char*)d_ws;
  u16* xb  = (u16*)(ws);
  u16* Wqp = (u16*)(ws + 8 * MB);
  u16* Wkp = (u16*)(ws + 12 * MB);
  u16* Wvp = (u16*)(ws + 16 * MB);
  u16* Wot = (u16*)(ws + 20 * MB);
  u8*  Qg  = (u8*)(ws + 24 * MB);
  u8*  Kg  = (u8*)(ws + (24 + 8 * (size_t)BB) * MB);
  u16* Vtg = (u16*)(ws + (24 + 16 * (size_t)BB) * MB);
  u16* Og  = (u16*)(ws + (24 + 32 * (size_t)BB) * MB);

  pack_x_kernel<<<dim3(4096), dim3(256), 0, stream>>>(x, xb);
  pack_wqkv_t<<<dim3(64, 8), dim3(256), 0, stream>>>(Wq, Wqp);
  pack_wqkv_t<<<dim3(64, 8), dim3(256), 0, stream>>>(Wk, Wkp);
  pack_wqkv_t<<<dim3(64, 8), dim3(256), 0, stream>>>(Wv, Wvp);
  pack_wo_t<<<dim3(64, 8), dim3(256), 0, stream>>>(Wo, Wot);

  const float qk_scale = 0.21022410381342865f;  // 1 / 512^0.25

  const int nchunk = 4 / BB;
  for (int c = 0; c < nchunk; ++c) {
    const u16* Ax = xb + (size_t)c * BB * 2048 * 512;
    gemm_bf16<0, 128><<<dim3(32, BB * 16), dim3(256), 0, stream>>>(Ax, Wqp, (void*)Qg, nullptr, 512, qk_scale);
    gemm_bf16<0, 128><<<dim3(32, BB * 16), dim3(256), 0, stream>>>(Ax, Wkp, (void*)Kg, nullptr, 512, qk_scale);
    gemm_bf16<1, 128><<<dim3(32, BB * 16), dim3(256), 0, stream>>>(Ax, Wvp, (void*)Vtg, nullptr, 512, 1.0f);

    attn_kernel<<<dim3(16 * BB * 8), dim3(512), 0, stream>>>(Qg, Kg, Vtg, Og, BB);

    gemm_bf16<2, 64><<<dim3(8, BB * 16), dim3(256), 0, stream>>>(
        Og, Wot, (void*)(out + (size_t)c * BB * 2048 * 512), bo, 4096, 1.0f);
  }
}